// Round 1
// baseline (76.240 us; speedup 1.0000x reference)
//
#include <hip/hip_runtime.h>
#include <math.h>

#define N_EDGES 4000000
#define HID 8
#define NPT 4   // edges per thread

__device__ __forceinline__ float fast_tanh(float v) {
    // tanh(v) = 1 - 2/(exp(2v)+1); exp(2v) = exp2(v * 2*log2(e))
    float e = exp2f(v * 2.8853900817779268f);
    return 1.0f - 2.0f * __builtin_amdgcn_rcpf(e + 1.0f);
}

template<int N>
__device__ __forceinline__ void ln_tanh(float (&h)[N][HID],
                                        const float* __restrict__ g,
                                        const float* __restrict__ be) {
    float m[N], r[N];
#pragma unroll
    for (int e = 0; e < N; ++e) {
        float s = 0.f;
#pragma unroll
        for (int j = 0; j < HID; ++j) s += h[e][j];
        m[e] = s * 0.125f;
        float v = 0.f;
#pragma unroll
        for (int j = 0; j < HID; ++j) { float d = h[e][j] - m[e]; v += d * d; }
        r[e] = __builtin_amdgcn_rsqf(v * 0.125f + 1e-5f);
    }
#pragma unroll
    for (int j = 0; j < HID; ++j) {
        const float gj = g[j], bj = be[j];
#pragma unroll
        for (int e = 0; e < N; ++e)
            h[e][j] = fast_tanh((h[e][j] - m[e]) * r[e] * gj + bj);
    }
}

template<int N>
__device__ __forceinline__ void linear8(float (&h)[N][HID],
                                        const float* __restrict__ W,
                                        const float* __restrict__ b) {
    float acc[N][HID];
#pragma unroll
    for (int j = 0; j < HID; ++j) {
        const float bj = b[j];
#pragma unroll
        for (int e = 0; e < N; ++e) acc[e][j] = bj;
    }
#pragma unroll
    for (int k = 0; k < HID; ++k) {
#pragma unroll
        for (int j = 0; j < HID; ++j) {
            const float w = W[k * HID + j];
#pragma unroll
            for (int e = 0; e < N; ++e) acc[e][j] += h[e][k] * w;
        }
    }
#pragma unroll
    for (int j = 0; j < HID; ++j)
#pragma unroll
        for (int e = 0; e < N; ++e) h[e][j] = acc[e][j];
}

__global__ __launch_bounds__(256) void edge_mlp_kernel(
    const float* __restrict__ x,
    const int*   __restrict__ ei,
    const float* __restrict__ W0, const float* __restrict__ b0,
    const float* __restrict__ g0, const float* __restrict__ be0,
    const float* __restrict__ W1, const float* __restrict__ b1,
    const float* __restrict__ g1, const float* __restrict__ be1,
    const float* __restrict__ W2, const float* __restrict__ b2,
    const float* __restrict__ g2, const float* __restrict__ be2,
    const float* __restrict__ W3, const float* __restrict__ b3,
    float* __restrict__ out)
{
    const int t = blockIdx.x * blockDim.x + threadIdx.x;
    const int base = t * NPT;
    if (base >= N_EDGES) return;

    // coalesced vector loads of the 4 start / 4 end indices
    const int4 sv = *reinterpret_cast<const int4*>(ei + base);
    const int4 dv = *reinterpret_cast<const int4*>(ei + N_EDGES + base);
    const int si[NPT] = {sv.x, sv.y, sv.z, sv.w};
    const int di[NPT] = {dv.x, dv.y, dv.z, dv.w};

    // gather node features (x table = 1.2 MB -> L2-resident)
    float xs[NPT][3], xd[NPT][3];
#pragma unroll
    for (int e = 0; e < NPT; ++e) {
#pragma unroll
        for (int c = 0; c < 3; ++c) {
            xs[e][c] = x[si[e] * 3 + c];
            xd[e][c] = x[di[e] * 3 + c];
        }
    }

    // layer 0: [6] @ W0[6][8] + b0
    float h[NPT][HID];
#pragma unroll
    for (int j = 0; j < HID; ++j) {
        const float w0 = W0[0 * HID + j], w1 = W0[1 * HID + j], w2 = W0[2 * HID + j];
        const float w3 = W0[3 * HID + j], w4 = W0[4 * HID + j], w5 = W0[5 * HID + j];
        const float bb = b0[j];
#pragma unroll
        for (int e = 0; e < NPT; ++e) {
            h[e][j] = bb + xs[e][0] * w0 + xs[e][1] * w1 + xs[e][2] * w2
                         + xd[e][0] * w3 + xd[e][1] * w4 + xd[e][2] * w5;
        }
    }

    ln_tanh<NPT>(h, g0, be0);
    linear8<NPT>(h, W1, b1);
    ln_tanh<NPT>(h, g1, be1);
    linear8<NPT>(h, W2, b2);
    ln_tanh<NPT>(h, g2, be2);

    // layer 3: [8] @ W3[8][1] + b3 -> scalar
    float o[NPT];
    const float bb3 = b3[0];
#pragma unroll
    for (int e = 0; e < NPT; ++e) o[e] = bb3;
#pragma unroll
    for (int k = 0; k < HID; ++k) {
        const float w = W3[k];
#pragma unroll
        for (int e = 0; e < NPT; ++e) o[e] += h[e][k] * w;
    }

    float4 ov = make_float4(o[0], o[1], o[2], o[3]);
    *reinterpret_cast<float4*>(out + base) = ov;
}

extern "C" void kernel_launch(void* const* d_in, const int* in_sizes, int n_in,
                              void* d_out, int out_size, void* d_ws, size_t ws_size,
                              hipStream_t stream) {
    const float* x   = (const float*)d_in[0];
    const int*   ei  = (const int*)d_in[1];
    const float* W0  = (const float*)d_in[2];
    const float* b0  = (const float*)d_in[3];
    const float* g0  = (const float*)d_in[4];
    const float* be0 = (const float*)d_in[5];
    const float* W1  = (const float*)d_in[6];
    const float* b1  = (const float*)d_in[7];
    const float* g1  = (const float*)d_in[8];
    const float* be1 = (const float*)d_in[9];
    const float* W2  = (const float*)d_in[10];
    const float* b2  = (const float*)d_in[11];
    const float* g2  = (const float*)d_in[12];
    const float* be2 = (const float*)d_in[13];
    const float* W3  = (const float*)d_in[14];
    const float* b3  = (const float*)d_in[15];
    float* out = (float*)d_out;

    const int nthreads = N_EDGES / NPT;          // 1,000,000
    const int blocks = (nthreads + 255) / 256;   // 3907
    edge_mlp_kernel<<<blocks, 256, 0, stream>>>(
        x, ei, W0, b0, g0, be0, W1, b1, g1, be1, W2, b2, g2, be2, W3, b3, out);
}

// Round 2
// 55.083 us; speedup vs baseline: 1.3841x; 1.3841x over previous
//
#include <hip/hip_runtime.h>

#define N_EDGES 4000000
#define HID 8
#define NPT 4
#define TWO_LOG2E 2.8853900817779268f
#define LN_EPS 1e-5f

// d_ws float layout (prepped weights)
#define O_W0  0      // 48: W0 column-centered
#define O_B0  48     // 8
#define O_GC0 56     // 8: g0 * 2log2e
#define O_BC0 64     // 8: be0 * 2log2e
#define O_W1  72     // 64: -2*(W1 col-centered-after-fold)
#define O_B1  136    // 8
#define O_GC1 144    // 8
#define O_BC1 152    // 8
#define O_W2  160    // 64
#define O_B2  224    // 8
#define O_GC2 232    // 8
#define O_BC2 240    // 8
#define O_W3  248    // 8: -2*W3
#define O_B3  256    // 1: b3 + colsum(W3)

__global__ void prep_kernel(
    const float* __restrict__ W0, const float* __restrict__ b0,
    const float* __restrict__ g0, const float* __restrict__ be0,
    const float* __restrict__ W1, const float* __restrict__ b1,
    const float* __restrict__ g1, const float* __restrict__ be1,
    const float* __restrict__ W2, const float* __restrict__ b2,
    const float* __restrict__ g2, const float* __restrict__ be2,
    const float* __restrict__ W3, const float* __restrict__ b3,
    float* __restrict__ ws)
{
    const int t = threadIdx.x;  // 64 threads

    // ---- layer 0: center columns of W0 (rows k over j), center b0 ----
    if (t < 48) {
        const int k = t >> 3;
        float m = 0.f;
#pragma unroll
        for (int jj = 0; jj < 8; ++jj) m += W0[k * 8 + jj];
        ws[O_W0 + t] = W0[t] - m * 0.125f;
    }
    if (t < 8) {
        float m = 0.f;
#pragma unroll
        for (int jj = 0; jj < 8; ++jj) m += b0[jj];
        ws[O_B0 + t] = b0[t] - m * 0.125f;
        ws[O_GC0 + t] = g0[t] * TWO_LOG2E;
        ws[O_BC0 + t] = be0[t] * TWO_LOG2E;
        ws[O_GC1 + t] = g1[t] * TWO_LOG2E;
        ws[O_BC1 + t] = be1[t] * TWO_LOG2E;
        ws[O_GC2 + t] = g2[t] * TWO_LOG2E;
        ws[O_BC2 + t] = be2[t] * TWO_LOG2E;
        ws[O_W3 + t] = -2.0f * W3[t];
    }

    // ---- layers 1,2: fold tanh-output affine (h = 1 - 2u):
    //   z_j = b_j + sum_k W_kj - 2 sum_k u_k W_kj  ->  W' = -2W, b' = b + colsum(W)
    // then center columns (over j) of (W', b') so LN mean == 0 ----
    {
        const int k = t >> 3;
        float rm1 = 0.f, rm2 = 0.f;
#pragma unroll
        for (int jj = 0; jj < 8; ++jj) { rm1 += W1[k * 8 + jj]; rm2 += W2[k * 8 + jj]; }
        // W' centered: -2*(W_kj - rowmean_k)   (row = input k, mean over output j)
        ws[O_W1 + t] = -2.0f * (W1[t] - rm1 * 0.125f);
        ws[O_W2 + t] = -2.0f * (W2[t] - rm2 * 0.125f);
    }
    if (t < 8) {
        float cs1 = 0.f, cs2 = 0.f;
#pragma unroll
        for (int k = 0; k < 8; ++k) { cs1 += W1[k * 8 + t]; cs2 += W2[k * 8 + t]; }
        float mb1 = 0.f, mb2 = 0.f;
#pragma unroll
        for (int j = 0; j < 8; ++j) { mb1 += b1[j]; mb2 += b2[j]; }
        float tot1 = 0.f, tot2 = 0.f;
#pragma unroll
        for (int i = 0; i < 64; ++i) { tot1 += W1[i]; tot2 += W2[i]; }
        // b' = b + colsum(W); centered: b' - mean_j(b')
        ws[O_B1 + t] = b1[t] + cs1 - mb1 * 0.125f - tot1 * 0.125f;
        ws[O_B2 + t] = b2[t] + cs2 - mb2 * 0.125f - tot2 * 0.125f;
    }
    if (t == 0) {
        float s = 0.f;
#pragma unroll
        for (int k = 0; k < 8; ++k) s += W3[k];
        ws[O_B3] = b3[0] + s;
    }
}

// LN (mean-free) + tanh, emitting u = rcp(exp2(fma)+1); tanh = 1-2u is folded
// into the NEXT layer's weights.
template<int N>
__device__ __forceinline__ void ln_tanh_u(float (&h)[N][HID],
                                          const float* __restrict__ gc,
                                          const float* __restrict__ bc) {
    float r[N];
#pragma unroll
    for (int e = 0; e < N; ++e) {
        float va = 0.f;
#pragma unroll
        for (int j = 0; j < HID; ++j) va = __builtin_fmaf(h[e][j], h[e][j], va);
        r[e] = __builtin_amdgcn_rsqf(__builtin_fmaf(va, 0.125f, LN_EPS));
    }
#pragma unroll
    for (int j = 0; j < HID; ++j) {
        const float gcj = gc[j], bcj = bc[j];
#pragma unroll
        for (int e = 0; e < N; ++e) {
            const float s = r[e] * gcj;
            const float y = __builtin_fmaf(h[e][j], s, bcj);
            const float ex = __builtin_amdgcn_exp2f(y);
            h[e][j] = __builtin_amdgcn_rcpf(ex + 1.0f);
        }
    }
}

template<int N>
__device__ __forceinline__ void linear8(float (&h)[N][HID],
                                        const float* __restrict__ W,
                                        const float* __restrict__ b) {
    float acc[N][HID];
#pragma unroll
    for (int j = 0; j < HID; ++j) {
        const float bj = b[j];
#pragma unroll
        for (int e = 0; e < N; ++e) acc[e][j] = bj;
    }
#pragma unroll
    for (int k = 0; k < HID; ++k) {
#pragma unroll
        for (int j = 0; j < HID; ++j) {
            const float w = W[k * HID + j];
#pragma unroll
            for (int e = 0; e < N; ++e) acc[e][j] = __builtin_fmaf(h[e][k], w, acc[e][j]);
        }
    }
#pragma unroll
    for (int j = 0; j < HID; ++j)
#pragma unroll
        for (int e = 0; e < N; ++e) h[e][j] = acc[e][j];
}

__global__ __launch_bounds__(256, 4) void edge_mlp_kernel(
    const float* __restrict__ x,
    const int*   __restrict__ ei,
    const float* __restrict__ ws,
    float* __restrict__ out)
{
    const int t = blockIdx.x * blockDim.x + threadIdx.x;
    const int base = t * NPT;
    if (base >= N_EDGES) return;

    const int4 sv = *reinterpret_cast<const int4*>(ei + base);
    const int4 dv = *reinterpret_cast<const int4*>(ei + N_EDGES + base);
    const int si[NPT] = {sv.x, sv.y, sv.z, sv.w};
    const int di[NPT] = {dv.x, dv.y, dv.z, dv.w};

    float xs[NPT][3], xd[NPT][3];
#pragma unroll
    for (int e = 0; e < NPT; ++e) {
#pragma unroll
        for (int c = 0; c < 3; ++c) {
            xs[e][c] = x[si[e] * 3 + c];
            xd[e][c] = x[di[e] * 3 + c];
        }
    }

    // layer 0 (centered weights)
    float h[NPT][HID];
#pragma unroll
    for (int j = 0; j < HID; ++j) {
        const float w0 = ws[O_W0 + 0 * HID + j], w1 = ws[O_W0 + 1 * HID + j],
                    w2 = ws[O_W0 + 2 * HID + j], w3 = ws[O_W0 + 3 * HID + j],
                    w4 = ws[O_W0 + 4 * HID + j], w5 = ws[O_W0 + 5 * HID + j];
        const float bb = ws[O_B0 + j];
#pragma unroll
        for (int e = 0; e < NPT; ++e) {
            float a = __builtin_fmaf(xs[e][0], w0, bb);
            a = __builtin_fmaf(xs[e][1], w1, a);
            a = __builtin_fmaf(xs[e][2], w2, a);
            a = __builtin_fmaf(xd[e][0], w3, a);
            a = __builtin_fmaf(xd[e][1], w4, a);
            h[e][j] = __builtin_fmaf(xd[e][2], w5, a);
        }
    }

    ln_tanh_u<NPT>(h, ws + O_GC0, ws + O_BC0);
    linear8<NPT>(h, ws + O_W1, ws + O_B1);
    ln_tanh_u<NPT>(h, ws + O_GC1, ws + O_BC1);
    linear8<NPT>(h, ws + O_W2, ws + O_B2);
    ln_tanh_u<NPT>(h, ws + O_GC2, ws + O_BC2);

    // final layer with folded tanh affine: out = b3' + sum u_k * (-2 W3_k)
    float o[NPT];
    const float bb3 = ws[O_B3];
#pragma unroll
    for (int e = 0; e < NPT; ++e) o[e] = bb3;
#pragma unroll
    for (int k = 0; k < HID; ++k) {
        const float w = ws[O_W3 + k];
#pragma unroll
        for (int e = 0; e < NPT; ++e) o[e] = __builtin_fmaf(h[e][k], w, o[e]);
    }

    *reinterpret_cast<float4*>(out + base) = make_float4(o[0], o[1], o[2], o[3]);
}

extern "C" void kernel_launch(void* const* d_in, const int* in_sizes, int n_in,
                              void* d_out, int out_size, void* d_ws, size_t ws_size,
                              hipStream_t stream) {
    const float* x   = (const float*)d_in[0];
    const int*   ei  = (const int*)d_in[1];
    const float* W0  = (const float*)d_in[2];
    const float* b0  = (const float*)d_in[3];
    const float* g0  = (const float*)d_in[4];
    const float* be0 = (const float*)d_in[5];
    const float* W1  = (const float*)d_in[6];
    const float* b1  = (const float*)d_in[7];
    const float* g1  = (const float*)d_in[8];
    const float* be1 = (const float*)d_in[9];
    const float* W2  = (const float*)d_in[10];
    const float* b2  = (const float*)d_in[11];
    const float* g2  = (const float*)d_in[12];
    const float* be2 = (const float*)d_in[13];
    const float* W3  = (const float*)d_in[14];
    const float* b3  = (const float*)d_in[15];
    float* out = (float*)d_out;
    float* ws  = (float*)d_ws;

    prep_kernel<<<1, 64, 0, stream>>>(W0, b0, g0, be0, W1, b1, g1, be1,
                                      W2, b2, g2, be2, W3, b3, ws);

    const int nthreads = N_EDGES / NPT;          // 1,000,000
    const int blocks = (nthreads + 255) / 256;   // 3907
    edge_mlp_kernel<<<blocks, 256, 0, stream>>>(x, ei, ws, out);
}